// Round 7
// baseline (809.007 us; speedup 1.0000x reference)
//
#include <hip/hip_runtime.h>

#define N_NODES 50000
#define N_EDGES 800000
#define IN_DIM  768
#define HID_DIM 512
#define OUT_DIM 256
#define M_PAD   50048   // 782 * 64

typedef __attribute__((ext_vector_type(8))) short shortx8;        // 8 bf16 = 16 B
typedef __attribute__((ext_vector_type(4))) short shortx4;        // 4 bf16 = 8 B
typedef __attribute__((ext_vector_type(4))) float floatx4;        // MFMA C/D + NT stores

#define AS1 __attribute__((address_space(1)))
#define AS3 __attribute__((address_space(3)))

__device__ __forceinline__ unsigned short f2bf_rne(float f) {
    unsigned int u = __float_as_uint(f);
    unsigned int r = u + 0x7FFFu + ((u >> 16) & 1u);
    return (unsigned short)(r >> 16);
}
__device__ __forceinline__ float bf2f(unsigned short h) {
    return __uint_as_float(((unsigned int)h) << 16);
}

// ---------------------------------------------------------------------------
// Graph prep
// ---------------------------------------------------------------------------
__global__ void count_deg_kernel(const int* __restrict__ dst, int* __restrict__ deg,
                                 int n_edges) {
    int e = blockIdx.x * blockDim.x + threadIdx.x;
    if (e < n_edges) atomicAdd(&deg[dst[e]], 1);
}

#define SCAN_B 256
#define N_SCAN_BLOCKS ((N_NODES + SCAN_B - 1) / SCAN_B)   // 196

__global__ void block_sum_kernel(const int* __restrict__ deg, int* __restrict__ partials,
                                 int n) {
    __shared__ int sm[SCAN_B];
    int i = blockIdx.x * SCAN_B + threadIdx.x;
    sm[threadIdx.x] = (i < n) ? deg[i] : 0;
    __syncthreads();
    for (int off = SCAN_B / 2; off > 0; off >>= 1) {
        if (threadIdx.x < off) sm[threadIdx.x] += sm[threadIdx.x + off];
        __syncthreads();
    }
    if (threadIdx.x == 0) partials[blockIdx.x] = sm[0];
}

__global__ void scan_partials_kernel(const int* __restrict__ partials,
                                     int* __restrict__ bases, int nb) {
    __shared__ int sm[SCAN_B];
    int v = (threadIdx.x < nb) ? partials[threadIdx.x] : 0;
    sm[threadIdx.x] = v;
    __syncthreads();
    for (int off = 1; off < SCAN_B; off <<= 1) {
        int t = (threadIdx.x >= off) ? sm[threadIdx.x - off] : 0;
        __syncthreads();
        sm[threadIdx.x] += t;
        __syncthreads();
    }
    if (threadIdx.x < nb) bases[threadIdx.x] = sm[threadIdx.x] - v;   // exclusive
}

__global__ void finalize_scan_kernel(const int* __restrict__ deg, const int* __restrict__ bases,
                                     int* __restrict__ offsets, int* __restrict__ cursor,
                                     float* __restrict__ dinv, int n) {
    __shared__ int sm[SCAN_B];
    int i = blockIdx.x * SCAN_B + threadIdx.x;
    int v = (i < n) ? deg[i] : 0;
    sm[threadIdx.x] = v;
    __syncthreads();
    for (int off = 1; off < SCAN_B; off <<= 1) {
        int t = (threadIdx.x >= off) ? sm[threadIdx.x - off] : 0;
        __syncthreads();
        sm[threadIdx.x] += t;
        __syncthreads();
    }
    if (i < n) {
        int incl = bases[blockIdx.x] + sm[threadIdx.x];
        int o = incl - v;
        offsets[i] = o;
        cursor[i]  = o;
        dinv[i]    = rsqrtf((float)(v + 1));
        if (i == n - 1) offsets[n] = incl;
    }
}

__global__ void fill_csr_kernel(const int* __restrict__ src, const int* __restrict__ dst,
                                int* __restrict__ cursor, int* __restrict__ csr_src,
                                int n_edges) {
    int e = blockIdx.x * blockDim.x + threadIdx.x;
    if (e < n_edges) {
        int p = atomicAdd(&cursor[dst[e]], 1);
        csr_src[p] = src[e];
    }
}

// ---------------------------------------------------------------------------
// fp32 -> bf16 hi/lo split
// ---------------------------------------------------------------------------
__global__ void convert_split_kernel(const float* __restrict__ x,
                                     unsigned short* __restrict__ xhi,
                                     unsigned short* __restrict__ xlo,
                                     long long n4) {
    long long i = (long long)blockIdx.x * blockDim.x + threadIdx.x;
    if (i >= n4) return;
    float4 v = *reinterpret_cast<const float4*>(x + i * 4);
    ushort4 h, l;
    h.x = f2bf_rne(v.x); l.x = f2bf_rne(v.x - bf2f(h.x));
    h.y = f2bf_rne(v.y); l.y = f2bf_rne(v.y - bf2f(h.y));
    h.z = f2bf_rne(v.z); l.z = f2bf_rne(v.z - bf2f(h.z));
    h.w = f2bf_rne(v.w); l.w = f2bf_rne(v.w - bf2f(h.w));
    *reinterpret_cast<ushort4*>(xhi + i * 4) = h;
    *reinterpret_cast<ushort4*>(xlo + i * 4) = l;
}

// ---------------------------------------------------------------------------
// W [K][N] fp32 -> Wt [N][K] bf16 hi/lo
// ---------------------------------------------------------------------------
__global__ void transpose_split_kernel(const float* __restrict__ W,
                                       unsigned short* __restrict__ Whi,
                                       unsigned short* __restrict__ Wlo,
                                       int K, int N) {
    __shared__ float tile[32][33];
    int n0 = blockIdx.x * 32, k0 = blockIdx.y * 32;
    int tx = threadIdx.x, ty = threadIdx.y;
    tile[ty][tx] = W[(size_t)(k0 + ty) * N + n0 + tx];
    __syncthreads();
    float v = tile[tx][ty];
    unsigned short h = f2bf_rne(v);
    size_t o = (size_t)(n0 + ty) * K + k0 + tx;
    Whi[o] = h;
    Wlo[o] = f2bf_rne(v - bf2f(h));
}

// ---------------------------------------------------------------------------
// bf16x3 split MFMA GEMM -- SINGLE-WAVE 64x64 TILE, BARRIER-FREE (round 6/7).
//   C[r][c] = bf16( (sum_k A[r][k]*B[c][k]) * dinv[r] )
//
// Why: r2-r5 showed MFMA pipe 33% / LDS pipe 27% busy -- neither saturated.
// The loss is CORRELATED stalling: 4-wave blocks lock-step at 2 barriers per
// K-step, all resident waves draining vmcnt together (m97 stall). One wave
// per block needs NO barrier at all (global_load_lds is wave-issued; a plain
// s_waitcnt vmcnt(0) orders stage->read), and 16 KB LDS/block gives 10
// fully INDEPENDENT waves/CU whose stalls decorrelate (m114).
//  - Per-wave work/math identical to one r2 wave -> bit-identical numerics.
//  - T1 XCD swizzle keeps same-A-panel col-blocks on one XCD (A restage
//    hits L2); T2 XOR swizzle unchanged (conflicts stay 0).
// ---------------------------------------------------------------------------
#define GBK 32

__global__ __launch_bounds__(64, 4)
void gemm_bf16x3_kernel(const unsigned short* __restrict__ Ahi,
                        const unsigned short* __restrict__ Alo,
                        const unsigned short* __restrict__ Bhi,
                        const unsigned short* __restrict__ Blo,
                        const float* __restrict__ dinv,
                        unsigned short* __restrict__ C,
                        int M, int N, int K) {
    // [hi/lo][row][k] : 2*64*32*2B = 8 KiB each, 16 KiB total -> 10 blocks/CU
    __shared__ __align__(16) unsigned short As[2][64][GBK];
    __shared__ __align__(16) unsigned short Bs[2][64][GBK];

    const int lane = threadIdx.x & 63;

    // --- XCD-aware bijective swizzle (m204 formula) ---
    const int gx   = gridDim.x;
    const int nwg  = gx * gridDim.y;
    const int blin = blockIdx.y * gx + blockIdx.x;      // hw linear id, x fastest
    const int qq   = nwg >> 3, rr = nwg & 7;
    const int xcd  = blin & 7, idx = blin >> 3;
    const int tt   = (xcd < rr ? xcd * (qq + 1) : rr * (qq + 1) + (xcd - rr) * qq) + idx;
    const int rowBase = (tt / gx) * 64;
    const int colBase = (tt % gx) * 64;

    // staging: one gload_lds instr covers 16 rows (4 lanes x 16B per row).
    // pre-swizzled global col-group so LDS[r][s] holds col-group s ^ ((r>>1)&3)
    const int cg   = ((lane & 3) ^ ((lane >> 3) & 3)) * 8;
    const int srow = lane >> 2;                          // 0..15
    const size_t aOff = (size_t)(rowBase + srow) * K + cg;
    const size_t bOff = (size_t)(colBase + srow) * K + cg;

    const int r16 = lane & 15;
    // matching read-side XOR: logical col-group (lane>>4), physical slot XORed
    const int kswz = ((lane >> 4) ^ ((r16 >> 1) & 3)) * 8;

    floatx4 acc[4][4] = {};

    for (int k0 = 0; k0 < K; k0 += GBK) {
        // all ds_reads of the previous step were consumed by its MFMAs
        // (compiler-inserted lgkmcnt); pin program order then stage.
        __builtin_amdgcn_sched_barrier(0);
#pragma unroll
        for (int j = 0; j < 4; j++) {
            __builtin_amdgcn_global_load_lds(
                (const AS1 void*)(Ahi + aOff + (size_t)(j * 16) * K + k0),
                (AS3 void*)(&As[0][j * 16][0]), 16, 0, 0);
            __builtin_amdgcn_global_load_lds(
                (const AS1 void*)(Alo + aOff + (size_t)(j * 16) * K + k0),
                (AS3 void*)(&As[1][j * 16][0]), 16, 0, 0);
            __builtin_amdgcn_global_load_lds(
                (const AS1 void*)(Bhi + bOff + (size_t)(j * 16) * K + k0),
                (AS3 void*)(&Bs[0][j * 16][0]), 16, 0, 0);
            __builtin_amdgcn_global_load_lds(
                (const AS1 void*)(Blo + bOff + (size_t)(j * 16) * K + k0),
                (AS3 void*)(&Bs[1][j * 16][0]), 16, 0, 0);
        }
        // wave-local: stage complete when vmcnt drains. No barrier needed.
        asm volatile("s_waitcnt vmcnt(0)" ::: "memory");
        __builtin_amdgcn_sched_barrier(0);

        // B fragments live across the whole K-step; A per-i (register diet)
        shortx8 bh[4], bv[4];
#pragma unroll
        for (int j = 0; j < 4; j++) {
            bh[j] = *reinterpret_cast<const shortx8*>(&Bs[0][j * 16 + r16][kswz]);
            bv[j] = *reinterpret_cast<const shortx8*>(&Bs[1][j * 16 + r16][kswz]);
        }
#pragma unroll
        for (int i = 0; i < 4; i++) {
            shortx8 ah = *reinterpret_cast<const shortx8*>(&As[0][i * 16 + r16][kswz]);
            shortx8 al = *reinterpret_cast<const shortx8*>(&As[1][i * 16 + r16][kswz]);
#pragma unroll
            for (int j = 0; j < 4; j++) {
                acc[i][j] = __builtin_amdgcn_mfma_f32_16x16x32_bf16(ah, bh[j], acc[i][j], 0, 0, 0);
                acc[i][j] = __builtin_amdgcn_mfma_f32_16x16x32_bf16(ah, bv[j], acc[i][j], 0, 0, 0);
                acc[i][j] = __builtin_amdgcn_mfma_f32_16x16x32_bf16(al, bh[j], acc[i][j], 0, 0, 0);
            }
        }
    }

#pragma unroll
    for (int i = 0; i < 4; i++) {
        int rsub = rowBase + i * 16 + (lane >> 4) * 4;
#pragma unroll
        for (int j = 0; j < 4; j++) {
            int col = colBase + j * 16 + r16;
#pragma unroll
            for (int r = 0; r < 4; r++) {
                int row = rsub + r;
                if (row < M) C[(size_t)row * N + col] = f2bf_rne(acc[i][j][r] * dinv[row]);
            }
        }
    }
}

// ---------------------------------------------------------------------------
// Aggregation, layer 1 -- wave-per-node, barrier-free (r5, kept).
// ---------------------------------------------------------------------------
__global__ __launch_bounds__(256)
void aggregate1_kernel(const unsigned short* __restrict__ hs, const int* __restrict__ offsets,
                       const int* __restrict__ csr_src, const float* __restrict__ dinv,
                       const float* __restrict__ bias,
                       unsigned short* __restrict__ yhi,
                       unsigned short* __restrict__ ylo) {
    const int wave = threadIdx.x >> 6;
    const int lane = threadIdx.x & 63;
    const int node = blockIdx.x * 4 + wave;
    const int c = lane * 8;
    const unsigned short* hp = hs + c;

    const int beg = offsets[node], end = offsets[node + 1];
    const float dv = dinv[node];
    floatx4 b0 = *reinterpret_cast<const floatx4*>(bias + c);
    floatx4 b1 = *reinterpret_cast<const floatx4*>(bias + c + 4);

    float acc[8];
    {
        shortx8 r = *reinterpret_cast<const shortx8*>(hp + (size_t)node * HID_DIM);
#pragma unroll
        for (int q = 0; q < 8; q++) acc[q] = bf2f((unsigned short)r[q]);
    }

#define A1_SUM8(r0,r1,r2,r3,r4,r5,r6,r7)                                        \
    _Pragma("unroll")                                                            \
    for (int q = 0; q < 8; q++)                                                  \
        acc[q] += ((bf2f((unsigned short)r0[q]) + bf2f((unsigned short)r1[q]))   \
                 + (bf2f((unsigned short)r2[q]) + bf2f((unsigned short)r3[q])))  \
                + ((bf2f((unsigned short)r4[q]) + bf2f((unsigned short)r5[q]))   \
                 + (bf2f((unsigned short)r6[q]) + bf2f((unsigned short)r7[q])));

    for (int base = beg; base < end; base += 64) {
        int cnt = min(64, end - base);
        int myidx = (base + lane < end) ? csr_src[base + lane] : 0;   // coalesced
        int j = 0;
        for (; j + 16 <= cnt; j += 16) {
            shortx8 r0 = *reinterpret_cast<const shortx8*>(hp + (size_t)__shfl(myidx, j + 0) * HID_DIM);
            shortx8 r1 = *reinterpret_cast<const shortx8*>(hp + (size_t)__shfl(myidx, j + 1) * HID_DIM);
            shortx8 r2 = *reinterpret_cast<const shortx8*>(hp + (size_t)__shfl(myidx, j + 2) * HID_DIM);
            shortx8 r3 = *reinterpret_cast<const shortx8*>(hp + (size_t)__shfl(myidx, j + 3) * HID_DIM);
            shortx8 r4 = *reinterpret_cast<const shortx8*>(hp + (size_t)__shfl(myidx, j + 4) * HID_DIM);
            shortx8 r5 = *reinterpret_cast<const shortx8*>(hp + (size_t)__shfl(myidx, j + 5) * HID_DIM);
            shortx8 r6 = *reinterpret_cast<const shortx8*>(hp + (size_t)__shfl(myidx, j + 6) * HID_DIM);
            shortx8 r7 = *reinterpret_cast<const shortx8*>(hp + (size_t)__shfl(myidx, j + 7) * HID_DIM);
            shortx8 r8 = *reinterpret_cast<const shortx8*>(hp + (size_t)__shfl(myidx, j + 8) * HID_DIM);
            shortx8 r9 = *reinterpret_cast<const shortx8*>(hp + (size_t)__shfl(myidx, j + 9) * HID_DIM);
            shortx8 ra = *reinterpret_cast<const shortx8*>(hp + (size_t)__shfl(myidx, j + 10) * HID_DIM);
            shortx8 rb = *reinterpret_cast<const shortx8*>(hp + (size_t)__shfl(myidx, j + 11) * HID_DIM);
            shortx8 rc = *reinterpret_cast<const shortx8*>(hp + (size_t)__shfl(myidx, j + 12) * HID_DIM);
            shortx8 rd = *reinterpret_cast<const shortx8*>(hp + (size_t)__shfl(myidx, j + 13) * HID_DIM);
            shortx8 re = *reinterpret_cast<const shortx8*>(hp + (size_t)__shfl(myidx, j + 14) * HID_DIM);
            shortx8 rf = *reinterpret_cast<const shortx8*>(hp + (size_t)__shfl(myidx, j + 15) * HID_DIM);
            A1_SUM8(r0, r1, r2, r3, r4, r5, r6, r7)
            A1_SUM8(r8, r9, ra, rb, rc, rd, re, rf)
        }
        for (; j + 8 <= cnt; j += 8) {
            shortx8 r0 = *reinterpret_cast<const shortx8*>(hp + (size_t)__shfl(myidx, j + 0) * HID_DIM);
            shortx8 r1 = *reinterpret_cast<const shortx8*>(hp + (size_t)__shfl(myidx, j + 1) * HID_DIM);
            shortx8 r2 = *reinterpret_cast<const shortx8*>(hp + (size_t)__shfl(myidx, j + 2) * HID_DIM);
            shortx8 r3 = *reinterpret_cast<const shortx8*>(hp + (size_t)__shfl(myidx, j + 3) * HID_DIM);
            shortx8 r4 = *reinterpret_cast<const shortx8*>(hp + (size_t)__shfl(myidx, j + 4) * HID_DIM);
            shortx8 r5 = *reinterpret_cast<const shortx8*>(hp + (size_t)__shfl(myidx, j + 5) * HID_DIM);
            shortx8 r6 = *reinterpret_cast<const shortx8*>(hp + (size_t)__shfl(myidx, j + 6) * HID_DIM);
            shortx8 r7 = *reinterpret_cast<const shortx8*>(hp + (size_t)__shfl(myidx, j + 7) * HID_DIM);
            A1_SUM8(r0, r1, r2, r3, r4, r5, r6, r7)
        }
        for (; j < cnt; j++) {
            shortx8 r = *reinterpret_cast<const shortx8*>(hp + (size_t)__shfl(myidx, j) * HID_DIM);
#pragma unroll
            for (int q = 0; q < 8; q++) acc[q] += bf2f((unsigned short)r[q]);
        }
    }
#undef A1_SUM8

    shortx8 h8, l8;
#pragma unroll
    for (int q = 0; q < 8; q++) {
        float bq = (q < 4) ? b0[q] : b1[q - 4];
        float o = fmaxf(acc[q] * dv + bq, 0.f);
        unsigned short h = f2bf_rne(o);
        h8[q] = (short)h;
        l8[q] = (short)f2bf_rne(o - bf2f(h));
    }
    __builtin_nontemporal_store(h8, reinterpret_cast<shortx8*>(yhi + (size_t)node * HID_DIM + c));
    __builtin_nontemporal_store(l8, reinterpret_cast<shortx8*>(ylo + (size_t)node * HID_DIM + c));
}

// ---------------------------------------------------------------------------
// Aggregation, layer 2 -- wave-per-node (r5, kept). fp32 out, NT store.
// ---------------------------------------------------------------------------
__global__ __launch_bounds__(256)
void aggregate2_kernel(const unsigned short* __restrict__ hs, const int* __restrict__ offsets,
                       const int* __restrict__ csr_src, const float* __restrict__ dinv,
                       const float* __restrict__ bias, float* __restrict__ out) {
    const int wave = threadIdx.x >> 6;
    const int lane = threadIdx.x & 63;
    const int node = blockIdx.x * 4 + wave;
    const int c = lane * 4;
    const unsigned short* hp = hs + c;

    const int beg = offsets[node], end = offsets[node + 1];
    const float dv = dinv[node];
    floatx4 b = *reinterpret_cast<const floatx4*>(bias + c);

    float acc[4];
    {
        shortx4 r = *reinterpret_cast<const shortx4*>(hp + (size_t)node * OUT_DIM);
#pragma unroll
        for (int q = 0; q < 4; q++) acc[q] = bf2f((unsigned short)r[q]);
    }

#define A2_SUM8(r0,r1,r2,r3,r4,r5,r6,r7)                                        \
    _Pragma("unroll")                                                            \
    for (int q = 0; q < 4; q++)                                                  \
        acc[q] += ((bf2f((unsigned short)r0[q]) + bf2f((unsigned short)r1[q]))   \
                 + (bf2f((unsigned short)r2[q]) + bf2f((unsigned short)r3[q])))  \
                + ((bf2f((unsigned short)r4[q]) + bf2f((unsigned short)r5[q]))   \
                 + (bf2f((unsigned short)r6[q]) + bf2f((unsigned short)r7[q])));

    for (int base = beg; base < end; base += 64) {
        int cnt = min(64, end - base);
        int myidx = (base + lane < end) ? csr_src[base + lane] : 0;   // coalesced
        int j = 0;
        for (; j + 16 <= cnt; j += 16) {
            shortx4 r0 = *reinterpret_cast<const shortx4*>(hp + (size_t)__shfl(myidx, j + 0) * OUT_DIM);
            shortx4 r1 = *reinterpret_cast<const shortx4*>(hp + (size_t)__shfl(myidx, j + 1) * OUT_DIM);
            shortx4 r2 = *reinterpret_cast<const shortx4*>(hp + (size_t)__shfl(myidx, j + 2) * OUT_DIM);
            shortx4 r3 = *reinterpret_cast<const shortx4*>(hp + (size_t)__shfl(myidx, j + 3) * OUT_DIM);
            shortx4 r4 = *reinterpret_cast<const shortx4*>(hp + (size_t)__shfl(myidx, j + 4) * OUT_DIM);
            shortx4 r5 = *reinterpret_cast<const shortx4*>(hp + (size_t)__shfl(myidx, j + 5) * OUT_DIM);
            shortx4 r6 = *reinterpret_cast<const shortx4*>(hp + (size_t)__shfl(myidx, j + 6) * OUT_DIM);
            shortx4 r7 = *reinterpret_cast<const shortx4*>(hp + (size_t)__shfl(myidx, j + 7) * OUT_DIM);
            shortx4 r8 = *reinterpret_cast<const shortx4*>(hp + (size_t)__shfl(myidx, j + 8) * OUT_DIM);
            shortx4 r9 = *reinterpret_cast<const shortx4*>(hp + (size_t)__shfl(myidx, j + 9) * OUT_DIM);
            shortx4 ra = *reinterpret_cast<const shortx4*>(hp + (size_t)__shfl(myidx, j + 10) * OUT_DIM);
            shortx4 rb = *reinterpret_cast<const shortx4*>(hp + (size_t)__shfl(myidx, j + 11) * OUT_DIM);
            shortx4 rc = *reinterpret_cast<const shortx4*>(hp + (size_t)__shfl(myidx, j + 12) * OUT_DIM);
            shortx4 rd = *reinterpret_cast<const shortx4*>(hp + (size_t)__shfl(myidx, j + 13) * OUT_DIM);
            shortx4 re = *reinterpret_cast<const shortx4*>(hp + (size_t)__shfl(myidx, j + 14) * OUT_DIM);
            shortx4 rf = *reinterpret_cast<const shortx4*>(hp + (size_t)__shfl(myidx, j + 15) * OUT_DIM);
            A2_SUM8(r0, r1, r2, r3, r4, r5, r6, r7)
            A2_SUM8(r8, r9, ra, rb, rc, rd, re, rf)
        }
        for (; j + 8 <= cnt; j += 8) {
            shortx4 r0 = *reinterpret_cast<const shortx4*>(hp + (size_t)__shfl(myidx, j + 0) * OUT_DIM);
            shortx4 r1 = *reinterpret_cast<const shortx4*>(hp + (size_t)__shfl(myidx, j + 1) * OUT_DIM);
            shortx4 r2 = *reinterpret_cast<const shortx4*>(hp + (size_t)__shfl(myidx, j + 2) * OUT_DIM);
            shortx4 r3 = *reinterpret_cast<const shortx4*>(hp + (size_t)__shfl(myidx, j + 3) * OUT_DIM);
            shortx4 r4 = *reinterpret_cast<const shortx4*>(hp + (size_t)__shfl(myidx, j + 4) * OUT_DIM);
            shortx4 r5 = *reinterpret_cast<const shortx4*>(hp + (size_t)__shfl(myidx, j + 5) * OUT_DIM);
            shortx4 r6 = *reinterpret_cast<const shortx4*>(hp + (size_t)__shfl(myidx, j + 6) * OUT_DIM);
            shortx4 r7 = *reinterpret_cast<const shortx4*>(hp + (size_t)__shfl(myidx, j + 7) * OUT_DIM);
            A2_SUM8(r0, r1, r2, r3, r4, r5, r6, r7)
        }
        for (; j < cnt; j++) {
            shortx4 r = *reinterpret_cast<const shortx4*>(hp + (size_t)__shfl(myidx, j) * OUT_DIM);
#pragma unroll
            for (int q = 0; q < 4; q++) acc[q] += bf2f((unsigned short)r[q]);
        }
    }
#undef A2_SUM8

    floatx4 o = { acc[0] * dv + b[0], acc[1] * dv + b[1],
                  acc[2] * dv + b[2], acc[3] * dv + b[3] };
    __builtin_nontemporal_store(o, reinterpret_cast<floatx4*>(out + (size_t)node * OUT_DIM + c));
}

// ---------------------------------------------------------------------------
extern "C" void kernel_launch(void* const* d_in, const int* in_sizes, int n_in,
                              void* d_out, int out_size, void* d_ws, size_t ws_size,
                              hipStream_t stream) {
    const float* x    = (const float*)d_in[0];
    const int*   edge = (const int*)d_in[1];
    const float* W1   = (const float*)d_in[2];
    const float* b1   = (const float*)d_in[3];
    const float* W2   = (const float*)d_in[4];
    const float* b2   = (const float*)d_in[5];
    float* out = (float*)d_out;

    const int* src = edge;
    const int* dst = edge + N_EDGES;

    char*  ws  = (char*)d_ws;
    size_t off = 0;
    auto alloc = [&](size_t bytes) -> void* {
        void* p = ws + off;
        off += (bytes + 255) & ~(size_t)255;
        return p;
    };
    int*   deg      = (int*)alloc((size_t)N_NODES * 4);
    float* dinv     = (float*)alloc((size_t)N_NODES * 4);
    int*   offsets  = (int*)alloc((size_t)(N_NODES + 1) * 4);
    int*   cursor   = (int*)alloc((size_t)N_NODES * 4);
    int*   csr_src  = (int*)alloc((size_t)N_EDGES * 4);
    int*   partials = (int*)alloc((size_t)N_SCAN_BLOCKS * 4);
    int*   bases    = (int*)alloc((size_t)N_SCAN_BLOCKS * 4);
    unsigned short* xhi   = (unsigned short*)alloc((size_t)M_PAD * IN_DIM * 2);
    unsigned short* xlo   = (unsigned short*)alloc((size_t)M_PAD * IN_DIM * 2);
    unsigned short* w1thi = (unsigned short*)alloc((size_t)HID_DIM * IN_DIM * 2);
    unsigned short* w1tlo = (unsigned short*)alloc((size_t)HID_DIM * IN_DIM * 2);
    unsigned short* w2thi = (unsigned short*)alloc((size_t)OUT_DIM * HID_DIM * 2);
    unsigned short* w2tlo = (unsigned short*)alloc((size_t)OUT_DIM * HID_DIM * 2);
    unsigned short* hs = (unsigned short*)alloc((size_t)N_NODES * HID_DIM * 2);  // bf16 pre-agg, reused L2

    unsigned short* y1hi = xhi;   // alias dead x regions
    unsigned short* y1lo = xlo;

    // ---- graph prep ----
    hipMemsetAsync(deg, 0, (size_t)N_NODES * 4, stream);
    count_deg_kernel<<<(N_EDGES + 255) / 256, 256, 0, stream>>>(dst, deg, N_EDGES);
    block_sum_kernel<<<N_SCAN_BLOCKS, SCAN_B, 0, stream>>>(deg, partials, N_NODES);
    scan_partials_kernel<<<1, SCAN_B, 0, stream>>>(partials, bases, N_SCAN_BLOCKS);
    finalize_scan_kernel<<<N_SCAN_BLOCKS, SCAN_B, 0, stream>>>(deg, bases, offsets, cursor,
                                                               dinv, N_NODES);
    fill_csr_kernel<<<(N_EDGES + 255) / 256, 256, 0, stream>>>(src, dst, cursor, csr_src, N_EDGES);

    // ---- precision split ----
    long long n4x = (long long)N_NODES * IN_DIM / 4;
    convert_split_kernel<<<(int)((n4x + 255) / 256), 256, 0, stream>>>(x, xhi, xlo, n4x);
    transpose_split_kernel<<<dim3(HID_DIM / 32, IN_DIM / 32), dim3(32, 32), 0, stream>>>(
        W1, w1thi, w1tlo, IN_DIM, HID_DIM);
    transpose_split_kernel<<<dim3(OUT_DIM / 32, HID_DIM / 32), dim3(32, 32), 0, stream>>>(
        W2, w2thi, w2tlo, HID_DIM, OUT_DIM);

    // ---- layer 1 ----
    gemm_bf16x3_kernel<<<dim3(HID_DIM / 64, M_PAD / 64), 64, 0, stream>>>(
        xhi, xlo, w1thi, w1tlo, dinv, hs, N_NODES, HID_DIM, IN_DIM);
    aggregate1_kernel<<<N_NODES / 4, 256, 0, stream>>>(
        hs, offsets, csr_src, dinv, b1, y1hi, y1lo);

    // ---- layer 2 ----
    gemm_bf16x3_kernel<<<dim3(OUT_DIM / 64, M_PAD / 64), 64, 0, stream>>>(
        y1hi, y1lo, w2thi, w2tlo, dinv, hs, N_NODES, OUT_DIM, HID_DIM);
    aggregate2_kernel<<<N_NODES / 4, 256, 0, stream>>>(
        hs, offsets, csr_src, dinv, b2, out);
}

// Round 9
// 789.227 us; speedup vs baseline: 1.0251x; 1.0251x over previous
//
#include <hip/hip_runtime.h>

#define N_NODES 50000
#define N_EDGES 800000
#define IN_DIM  768
#define HID_DIM 512
#define OUT_DIM 256
#define M_PAD   50176   // 196 * 256 (also 392 * 128)

typedef __attribute__((ext_vector_type(8))) short shortx8;        // 8 bf16 = 16 B
typedef __attribute__((ext_vector_type(4))) short shortx4;        // 4 bf16 = 8 B
typedef __attribute__((ext_vector_type(4))) float floatx4;        // MFMA C/D + NT stores

#define AS1 __attribute__((address_space(1)))
#define AS3 __attribute__((address_space(3)))

__device__ __forceinline__ unsigned short f2bf_rne(float f) {
    unsigned int u = __float_as_uint(f);
    unsigned int r = u + 0x7FFFu + ((u >> 16) & 1u);
    return (unsigned short)(r >> 16);
}
__device__ __forceinline__ float bf2f(unsigned short h) {
    return __uint_as_float(((unsigned int)h) << 16);
}

// ---------------------------------------------------------------------------
// Graph prep
// ---------------------------------------------------------------------------
__global__ void count_deg_kernel(const int* __restrict__ dst, int* __restrict__ deg,
                                 int n_edges) {
    int e = blockIdx.x * blockDim.x + threadIdx.x;
    if (e < n_edges) atomicAdd(&deg[dst[e]], 1);
}

#define SCAN_B 256
#define N_SCAN_BLOCKS ((N_NODES + SCAN_B - 1) / SCAN_B)   // 196

__global__ void block_sum_kernel(const int* __restrict__ deg, int* __restrict__ partials,
                                 int n) {
    __shared__ int sm[SCAN_B];
    int i = blockIdx.x * SCAN_B + threadIdx.x;
    sm[threadIdx.x] = (i < n) ? deg[i] : 0;
    __syncthreads();
    for (int off = SCAN_B / 2; off > 0; off >>= 1) {
        if (threadIdx.x < off) sm[threadIdx.x] += sm[threadIdx.x + off];
        __syncthreads();
    }
    if (threadIdx.x == 0) partials[blockIdx.x] = sm[0];
}

__global__ void scan_partials_kernel(const int* __restrict__ partials,
                                     int* __restrict__ bases, int nb) {
    __shared__ int sm[SCAN_B];
    int v = (threadIdx.x < nb) ? partials[threadIdx.x] : 0;
    sm[threadIdx.x] = v;
    __syncthreads();
    for (int off = 1; off < SCAN_B; off <<= 1) {
        int t = (threadIdx.x >= off) ? sm[threadIdx.x - off] : 0;
        __syncthreads();
        sm[threadIdx.x] += t;
        __syncthreads();
    }
    if (threadIdx.x < nb) bases[threadIdx.x] = sm[threadIdx.x] - v;   // exclusive
}

__global__ void finalize_scan_kernel(const int* __restrict__ deg, const int* __restrict__ bases,
                                     int* __restrict__ offsets, int* __restrict__ cursor,
                                     float* __restrict__ dinv, int n) {
    __shared__ int sm[SCAN_B];
    int i = blockIdx.x * SCAN_B + threadIdx.x;
    int v = (i < n) ? deg[i] : 0;
    sm[threadIdx.x] = v;
    __syncthreads();
    for (int off = 1; off < SCAN_B; off <<= 1) {
        int t = (threadIdx.x >= off) ? sm[threadIdx.x - off] : 0;
        __syncthreads();
        sm[threadIdx.x] += t;
        __syncthreads();
    }
    if (i < n) {
        int incl = bases[blockIdx.x] + sm[threadIdx.x];
        int o = incl - v;
        offsets[i] = o;
        cursor[i]  = o;
        dinv[i]    = rsqrtf((float)(v + 1));
        if (i == n - 1) offsets[n] = incl;
    }
}

__global__ void fill_csr_kernel(const int* __restrict__ src, const int* __restrict__ dst,
                                int* __restrict__ cursor, int* __restrict__ csr_src,
                                int n_edges) {
    int e = blockIdx.x * blockDim.x + threadIdx.x;
    if (e < n_edges) {
        int p = atomicAdd(&cursor[dst[e]], 1);
        csr_src[p] = src[e];
    }
}

// ---------------------------------------------------------------------------
// fp32 -> bf16 hi/lo split
// ---------------------------------------------------------------------------
__global__ void convert_split_kernel(const float* __restrict__ x,
                                     unsigned short* __restrict__ xhi,
                                     unsigned short* __restrict__ xlo,
                                     long long n4) {
    long long i = (long long)blockIdx.x * blockDim.x + threadIdx.x;
    if (i >= n4) return;
    float4 v = *reinterpret_cast<const float4*>(x + i * 4);
    ushort4 h, l;
    h.x = f2bf_rne(v.x); l.x = f2bf_rne(v.x - bf2f(h.x));
    h.y = f2bf_rne(v.y); l.y = f2bf_rne(v.y - bf2f(h.y));
    h.z = f2bf_rne(v.z); l.z = f2bf_rne(v.z - bf2f(h.z));
    h.w = f2bf_rne(v.w); l.w = f2bf_rne(v.w - bf2f(h.w));
    *reinterpret_cast<ushort4*>(xhi + i * 4) = h;
    *reinterpret_cast<ushort4*>(xlo + i * 4) = l;
}

// ---------------------------------------------------------------------------
// W [K][N] fp32 -> Wt [N][K] bf16 hi/lo
// ---------------------------------------------------------------------------
__global__ void transpose_split_kernel(const float* __restrict__ W,
                                       unsigned short* __restrict__ Whi,
                                       unsigned short* __restrict__ Wlo,
                                       int K, int N) {
    __shared__ float tile[32][33];
    int n0 = blockIdx.x * 32, k0 = blockIdx.y * 32;
    int tx = threadIdx.x, ty = threadIdx.y;
    tile[ty][tx] = W[(size_t)(k0 + ty) * N + n0 + tx];
    __syncthreads();
    float v = tile[tx][ty];
    unsigned short h = f2bf_rne(v);
    size_t o = (size_t)(n0 + ty) * K + k0 + tx;
    Whi[o] = h;
    Wlo[o] = f2bf_rne(v - bf2f(h));
}

// ---------------------------------------------------------------------------
// GEMM layer-1: 256x128 tile, 8 waves, counted-vmcnt double-buffer pipeline.
//   C[r][c] = bf16( (sum_k A[r][k]*B[c][k]) * dinv[r] )
//
// Rationale (r2..r7 evidence): the 128-sq/4-wave/2-barrier structure is
// pinned at ~173us (683 TF, both MFMA and LDS pipes <35% busy) by the
// vmcnt(0)-drain at every barrier. The catalog's regime gate: counted-vmcnt
// (T4) pays only in the 8-wave big-tile schedule (m218: +38-73%), not as a
// graft (r4 null). This kernel is that schedule, adapted for bf16x3:
//  - BM=256 BN=128 BK=32, 512 thr = 8 waves (4M x 2N), wave tile 64x64 --
//    per-wave math IDENTICAL to r2 -> bit-identical numerics.
//  - LDS 96 KiB: As[2][2][256][32] + Bs[2][2][128][32], 1 block/CU.
//  - Per K-step: {16 ds_read -> lgkmcnt(0)+s_barrier (buf provably free)}
//    then {stage t+2 (6 gload_lds) -> setprio(1) 48 MFMA setprio(0) ->
//    vmcnt(6)+s_barrier}. vmcnt NEVER drains to 0 in the main loop: t+1's
//    6 loads proven landed while t+2's 6 stay in flight across the barrier.
//  - T1 XCD swizzle + T2 XOR swizzle unchanged.
// ---------------------------------------------------------------------------
#define GBK 32

__global__ __launch_bounds__(512, 2)
void gemm1_256x128_kernel(const unsigned short* __restrict__ Ahi,
                          const unsigned short* __restrict__ Alo,
                          const unsigned short* __restrict__ Bhi,
                          const unsigned short* __restrict__ Blo,
                          const float* __restrict__ dinv,
                          unsigned short* __restrict__ C,
                          int M, int N, int K) {
    __shared__ __align__(16) unsigned short As[2][2][256][GBK];   // 64 KiB
    __shared__ __align__(16) unsigned short Bs[2][2][128][GBK];   // 32 KiB

    const int tid  = threadIdx.x;
    const int lane = tid & 63;
    const int wave = tid >> 6;          // 0..7
    const int wr   = wave >> 1;         // 0..3 -> m-offset wr*64
    const int wc   = wave & 1;          // 0..1 -> n-offset wc*64

    // --- XCD-aware bijective swizzle (m204) ---
    const int gx   = gridDim.x;                         // N/128
    const int nwg  = gx * gridDim.y;
    const int blin = blockIdx.y * gx + blockIdx.x;
    const int qq   = nwg >> 3, rr = nwg & 7;
    const int xcd  = blin & 7, idx = blin >> 3;
    const int tt   = (xcd < rr ? xcd * (qq + 1) : rr * (qq + 1) + (xcd - rr) * qq) + idx;
    const int rowBase = (tt / gx) * 256;
    const int colBase = (tt % gx) * 128;

    // --- staging map: thread t covers row (t>>2), 16B slot (t&3), T2-preswz
    const int slot = tid & 3;
    const int arow = tid >> 2;                          // 0..127
    const int cg   = (slot ^ ((tid >> 3) & 3)) * 8;     // = slot ^ ((row>>1)&3)
    const size_t aOff = (size_t)(rowBase + arow) * K + cg;
    const size_t bOff = (size_t)(colBase + arow) * K + cg;

    const int r16  = lane & 15;
    const int kswz = ((lane >> 4) ^ ((r16 >> 1) & 3)) * 8;
    const int m0   = wr * 64;
    const int n0   = wc * 64;

    floatx4 acc[4][4] = {};
    const int nt = K / GBK;             // 24

    // 6 gload_lds per wave per tile: A-hi q0/q1, A-lo q0/q1, B-hi, B-lo
    auto STAGE = [&](int t, int buf) {
        const size_t k0 = (size_t)t * GBK;
        unsigned short* ah0 = &As[buf][0][0][0] + (size_t)tid * 8;
        unsigned short* al0 = &As[buf][1][0][0] + (size_t)tid * 8;
        unsigned short* bh0 = &Bs[buf][0][0][0] + (size_t)tid * 8;
        unsigned short* bl0 = &Bs[buf][1][0][0] + (size_t)tid * 8;
        __builtin_amdgcn_global_load_lds((const AS1 void*)(Ahi + aOff + k0),
                                         (AS3 void*)ah0, 16, 0, 0);
        __builtin_amdgcn_global_load_lds((const AS1 void*)(Ahi + aOff + (size_t)128 * K + k0),
                                         (AS3 void*)(ah0 + 128 * GBK), 16, 0, 0);
        __builtin_amdgcn_global_load_lds((const AS1 void*)(Alo + aOff + k0),
                                         (AS3 void*)al0, 16, 0, 0);
        __builtin_amdgcn_global_load_lds((const AS1 void*)(Alo + aOff + (size_t)128 * K + k0),
                                         (AS3 void*)(al0 + 128 * GBK), 16, 0, 0);
        __builtin_amdgcn_global_load_lds((const AS1 void*)(Bhi + bOff + k0),
                                         (AS3 void*)bh0, 16, 0, 0);
        __builtin_amdgcn_global_load_lds((const AS1 void*)(Blo + bOff + k0),
                                         (AS3 void*)bl0, 16, 0, 0);
    };

    // prologue: stage tiles 0,1; wait tile0 only (tile1's 6 stay in flight)
    STAGE(0, 0);
    STAGE(1, 1);
    asm volatile("s_waitcnt vmcnt(6)\n\ts_barrier" ::: "memory");
    __builtin_amdgcn_sched_barrier(0);

    int cur = 0;
    for (int t = 0; t < nt; ++t) {
        // ---- phase 1: all fragment reads from buf[cur] ----
        shortx8 ah[4], al[4], bh[4], bl[4];
#pragma unroll
        for (int i = 0; i < 4; i++) {
            ah[i] = *reinterpret_cast<const shortx8*>(&As[cur][0][m0 + i * 16 + r16][kswz]);
            al[i] = *reinterpret_cast<const shortx8*>(&As[cur][1][m0 + i * 16 + r16][kswz]);
            bh[i] = *reinterpret_cast<const shortx8*>(&Bs[cur][0][n0 + i * 16 + r16][kswz]);
            bl[i] = *reinterpret_cast<const shortx8*>(&Bs[cur][1][n0 + i * 16 + r16][kswz]);
        }
        asm volatile("s_waitcnt lgkmcnt(0)\n\ts_barrier" ::: "memory");
        __builtin_amdgcn_sched_barrier(0);
        // buf[cur] is now provably free across the whole block.

        // ---- phase 2: stage t+2 into buf[cur] (stays in flight), MFMA ----
        if (t + 2 < nt) STAGE(t + 2, cur);

        __builtin_amdgcn_s_setprio(1);
#pragma unroll
        for (int i = 0; i < 4; i++)
#pragma unroll
            for (int j = 0; j < 4; j++) {
                acc[i][j] = __builtin_amdgcn_mfma_f32_16x16x32_bf16(ah[i], bh[j], acc[i][j], 0, 0, 0);
                acc[i][j] = __builtin_amdgcn_mfma_f32_16x16x32_bf16(ah[i], bl[j], acc[i][j], 0, 0, 0);
                acc[i][j] = __builtin_amdgcn_mfma_f32_16x16x32_bf16(al[i], bh[j], acc[i][j], 0, 0, 0);
            }
        __builtin_amdgcn_s_setprio(0);

        if (t + 1 < nt) {
            if (t + 2 < nt) asm volatile("s_waitcnt vmcnt(6)\n\ts_barrier" ::: "memory");
            else            asm volatile("s_waitcnt vmcnt(0)\n\ts_barrier" ::: "memory");
            __builtin_amdgcn_sched_barrier(0);
        }
        cur ^= 1;
    }

#pragma unroll
    for (int i = 0; i < 4; i++) {
        int rsub = rowBase + m0 + i * 16 + (lane >> 4) * 4;
#pragma unroll
        for (int j = 0; j < 4; j++) {
            int col = colBase + n0 + j * 16 + r16;
#pragma unroll
            for (int r = 0; r < 4; r++) {
                int row = rsub + r;
                if (row < M) C[(size_t)row * N + col] = f2bf_rne(acc[i][j][r] * dinv[row]);
            }
        }
    }
}

// ---------------------------------------------------------------------------
// GEMM (r2 verified structure) -- used for layer 2 (well-balanced grid).
// ---------------------------------------------------------------------------
__global__ __launch_bounds__(256, 4)
void gemm_bf16x3_kernel(const unsigned short* __restrict__ Ahi,
                        const unsigned short* __restrict__ Alo,
                        const unsigned short* __restrict__ Bhi,
                        const unsigned short* __restrict__ Blo,
                        const float* __restrict__ dinv,
                        unsigned short* __restrict__ C,
                        int M, int N, int K) {
    __shared__ __align__(16) unsigned short As[2][128][GBK];
    __shared__ __align__(16) unsigned short Bs[2][128][GBK];

    const int tid  = threadIdx.x;
    const int lane = tid & 63;
    const int wave = tid >> 6;

    const int gx   = gridDim.x;
    const int nwg  = gx * gridDim.y;
    const int blin = blockIdx.y * gx + blockIdx.x;
    const int qq   = nwg >> 3, rr = nwg & 7;
    const int xcd  = blin & 7, idx = blin >> 3;
    const int tt   = (xcd < rr ? xcd * (qq + 1) : rr * (qq + 1) + (xcd - rr) * qq) + idx;
    const int rowBase = (tt / gx) * 128;
    const int colBase = (tt % gx) * 128;

    const unsigned short* gsrc =
        (wave == 0) ? Ahi : (wave == 1) ? Alo : (wave == 2) ? Bhi : Blo;
    unsigned short* lbase =
        (wave == 0) ? &As[0][0][0] : (wave == 1) ? &As[1][0][0]
      : (wave == 2) ? &Bs[0][0][0] : &Bs[1][0][0];
    const int rbase = (wave < 2) ? rowBase : colBase;
    const int cg = ((lane & 3) ^ ((lane >> 3) & 3)) * 8;
    const size_t laneRowOff = (size_t)(rbase + (lane >> 2)) * K + cg;

    const int m0  = (wave & 1) * 64;
    const int n0  = (wave >> 1) * 64;
    const int r16 = lane & 15;
    const int kswz = ((lane >> 4) ^ ((r16 >> 1) & 3)) * 8;

    floatx4 acc[4][4] = {};

    for (int k0 = 0; k0 < K; k0 += GBK) {
#pragma unroll
        for (int j = 0; j < 8; j++) {
            const unsigned short* g = gsrc + laneRowOff + (size_t)(j * 16) * K + k0;
            __builtin_amdgcn_global_load_lds((const AS1 void*)g,
                                             (AS3 void*)(lbase + j * 16 * GBK),
                                             16, 0, 0);
        }
        __syncthreads();

        shortx8 bh[4], bv[4];
#pragma unroll
        for (int j = 0; j < 4; j++) {
            bh[j] = *reinterpret_cast<const shortx8*>(&Bs[0][n0 + j * 16 + r16][kswz]);
            bv[j] = *reinterpret_cast<const shortx8*>(&Bs[1][n0 + j * 16 + r16][kswz]);
        }
#pragma unroll
        for (int i = 0; i < 4; i++) {
            shortx8 ah = *reinterpret_cast<const shortx8*>(&As[0][m0 + i * 16 + r16][kswz]);
            shortx8 al = *reinterpret_cast<const shortx8*>(&As[1][m0 + i * 16 + r16][kswz]);
#pragma unroll
            for (int j = 0; j < 4; j++) {
                acc[i][j] = __builtin_amdgcn_mfma_f32_16x16x32_bf16(ah, bh[j], acc[i][j], 0, 0, 0);
                acc[i][j] = __builtin_amdgcn_mfma_f32_16x16x32_bf16(ah, bv[j], acc[i][j], 0, 0, 0);
                acc[i][j] = __builtin_amdgcn_mfma_f32_16x16x32_bf16(al, bh[j], acc[i][j], 0, 0, 0);
            }
        }
        __syncthreads();
    }

#pragma unroll
    for (int i = 0; i < 4; i++) {
        int rsub = rowBase + m0 + i * 16 + (lane >> 4) * 4;
#pragma unroll
        for (int j = 0; j < 4; j++) {
            int col = colBase + n0 + j * 16 + r16;
#pragma unroll
            for (int r = 0; r < 4; r++) {
                int row = rsub + r;
                if (row < M) C[(size_t)row * N + col] = f2bf_rne(acc[i][j][r] * dinv[row]);
            }
        }
    }
}

// ---------------------------------------------------------------------------
// Aggregation, layer 1 -- wave-per-node, barrier-free (r5, kept).
// ---------------------------------------------------------------------------
__global__ __launch_bounds__(256)
void aggregate1_kernel(const unsigned short* __restrict__ hs, const int* __restrict__ offsets,
                       const int* __restrict__ csr_src, const float* __restrict__ dinv,
                       const float* __restrict__ bias,
                       unsigned short* __restrict__ yhi,
                       unsigned short* __restrict__ ylo) {
    const int wave = threadIdx.x >> 6;
    const int lane = threadIdx.x & 63;
    const int node = blockIdx.x * 4 + wave;
    const int c = lane * 8;
    const unsigned short* hp = hs + c;

    const int beg = offsets[node], end = offsets[node + 1];
    const float dv = dinv[node];
    floatx4 b0 = *reinterpret_cast<const floatx4*>(bias + c);
    floatx4 b1 = *reinterpret_cast<const floatx4*>(bias + c + 4);

    float acc[8];
    {
        shortx8 r = *reinterpret_cast<const shortx8*>(hp + (size_t)node * HID_DIM);
#pragma unroll
        for (int q = 0; q < 8; q++) acc[q] = bf2f((unsigned short)r[q]);
    }

#define A1_SUM8(r0,r1,r2,r3,r4,r5,r6,r7)                                        \
    _Pragma("unroll")                                                            \
    for (int q = 0; q < 8; q++)                                                  \
        acc[q] += ((bf2f((unsigned short)r0[q]) + bf2f((unsigned short)r1[q]))   \
                 + (bf2f((unsigned short)r2[q]) + bf2f((unsigned short)r3[q])))  \
                + ((bf2f((unsigned short)r4[q]) + bf2f((unsigned short)r5[q]))   \
                 + (bf2f((unsigned short)r6[q]) + bf2f((unsigned short)r7[q])));

    for (int base = beg; base < end; base += 64) {
        int cnt = min(64, end - base);
        int myidx = (base + lane < end) ? csr_src[base + lane] : 0;   // coalesced
        int j = 0;
        for (; j + 16 <= cnt; j += 16) {
            shortx8 r0 = *reinterpret_cast<const shortx8*>(hp + (size_t)__shfl(myidx, j + 0) * HID_DIM);
            shortx8 r1 = *reinterpret_cast<const shortx8*>(hp + (size_t)__shfl(myidx, j + 1) * HID_DIM);
            shortx8 r2 = *reinterpret_cast<const shortx8*>(hp + (size_t)__shfl(myidx, j + 2) * HID_DIM);
            shortx8 r3 = *reinterpret_cast<const shortx8*>(hp + (size_t)__shfl(myidx, j + 3) * HID_DIM);
            shortx8 r4 = *reinterpret_cast<const shortx8*>(hp + (size_t)__shfl(myidx, j + 4) * HID_DIM);
            shortx8 r5 = *reinterpret_cast<const shortx8*>(hp + (size_t)__shfl(myidx, j + 5) * HID_DIM);
            shortx8 r6 = *reinterpret_cast<const shortx8*>(hp + (size_t)__shfl(myidx, j + 6) * HID_DIM);
            shortx8 r7 = *reinterpret_cast<const shortx8*>(hp + (size_t)__shfl(myidx, j + 7) * HID_DIM);
            shortx8 r8 = *reinterpret_cast<const shortx8*>(hp + (size_t)__shfl(myidx, j + 8) * HID_DIM);
            shortx8 r9 = *reinterpret_cast<const shortx8*>(hp + (size_t)__shfl(myidx, j + 9) * HID_DIM);
            shortx8 ra = *reinterpret_cast<const shortx8*>(hp + (size_t)__shfl(myidx, j + 10) * HID_DIM);
            shortx8 rb = *reinterpret_cast<const shortx8*>(hp + (size_t)__shfl(myidx, j + 11) * HID_DIM);
            shortx8 rc = *reinterpret_cast<const shortx8*>(hp + (size_t)__shfl(myidx, j + 12) * HID_DIM);
            shortx8 rd = *reinterpret_cast<const shortx8*>(hp + (size_t)__shfl(myidx, j + 13) * HID_DIM);
            shortx8 re = *reinterpret_cast<const shortx8*>(hp + (size_t)__shfl(myidx, j + 14) * HID_DIM);
            shortx8 rf = *reinterpret_cast<const shortx8*>(hp + (size_t)__shfl(myidx, j + 15) * HID_DIM);
            A1_SUM8(r0, r1, r2, r3, r4, r5, r6, r7)
            A1_SUM8(r8, r9, ra, rb, rc, rd, re, rf)
        }
        for (; j + 8 <= cnt; j += 8) {
            shortx8 r0 = *reinterpret_cast<const shortx8*>(hp + (size_t)__shfl(myidx, j + 0) * HID_DIM);
            shortx8 r1 = *reinterpret_cast<const shortx8*>(hp + (size_t)__shfl(myidx, j + 1) * HID_DIM);
            shortx8 r2 = *reinterpret_cast<const shortx8*>(hp + (size_t)__shfl(myidx, j + 2) * HID_DIM);
            shortx8 r3 = *reinterpret_cast<const shortx8*>(hp + (size_t)__shfl(myidx, j + 3) * HID_DIM);
            shortx8 r4 = *reinterpret_cast<const shortx8*>(hp + (size_t)__shfl(myidx, j + 4) * HID_DIM);
            shortx8 r5 = *reinterpret_cast<const shortx8*>(hp + (size_t)__shfl(myidx, j + 5) * HID_DIM);
            shortx8 r6 = *reinterpret_cast<const shortx8*>(hp + (size_t)__shfl(myidx, j + 6) * HID_DIM);
            shortx8 r7 = *reinterpret_cast<const shortx8*>(hp + (size_t)__shfl(myidx, j + 7) * HID_DIM);
            A1_SUM8(r0, r1, r2, r3, r4, r5, r6, r7)
        }
        for (; j < cnt; j++) {
            shortx8 r = *reinterpret_cast<const shortx8*>(hp + (size_t)__shfl(myidx, j) * HID_DIM);
#pragma unroll
            for (int q = 0; q < 8; q++) acc[q] += bf2f((unsigned short)r[q]);
        }
    }
#undef A1_SUM8

    shortx8 h8, l8;
#pragma unroll
    for (int q = 0; q < 8; q++) {
        float bq = (q < 4) ? b0[q] : b1[q - 4];
        float o = fmaxf(acc[q] * dv + bq, 0.f);
        unsigned short h = f2bf_rne(o);
        h8[q] = (short)h;
        l8[q] = (short)f2bf_rne(o - bf2f(h));
    }
    __builtin_nontemporal_store(h8, reinterpret_cast<shortx8*>(yhi + (size_t)node * HID_DIM + c));
    __builtin_nontemporal_store(l8, reinterpret_cast<shortx8*>(ylo + (size_t)node * HID_DIM + c));
}

// ---------------------------------------------------------------------------
// Aggregation, layer 2 -- wave-per-node (r5, kept). fp32 out, NT store.
// ---------------------------------------------------------------------------
__global__ __launch_bounds__(256)
void aggregate2_kernel(const unsigned short* __restrict__ hs, const int* __restrict__ offsets,
                       const int* __restrict__ csr_src, const float* __restrict__ dinv,
                       const float* __restrict__ bias, float* __restrict__ out) {
    const int wave = threadIdx.x >> 6;
    const int lane = threadIdx.x & 63;
    const int node = blockIdx.x * 4 + wave;
    const int c = lane * 4;
    const unsigned short* hp = hs + c;

    const int beg = offsets[node], end = offsets[node + 1];
    const float dv = dinv[node];
    floatx4 b = *reinterpret_cast<const floatx4*>(bias + c);

    float acc[4];
    {
        shortx4 r = *reinterpret_cast<const shortx4*>(hp + (size_t)node * OUT_DIM);
#pragma unroll
        for (int q = 0; q < 4; q++) acc[q] = bf2f((unsigned short)r[q]);
    }

#define A2_SUM8(r0,r1,r2,r3,r4,r5,r6,r7)                                        \
    _Pragma("unroll")                                                            \
    for (int q = 0; q < 4; q++)                                                  \
        acc[q] += ((bf2f((unsigned short)r0[q]) + bf2f((unsigned short)r1[q]))   \
                 + (bf2f((unsigned short)r2[q]) + bf2f((unsigned short)r3[q])))  \
                + ((bf2f((unsigned short)r4[q]) + bf2f((unsigned short)r5[q]))   \
                 + (bf2f((unsigned short)r6[q]) + bf2f((unsigned short)r7[q])));

    for (int base = beg; base < end; base += 64) {
        int cnt = min(64, end - base);
        int myidx = (base + lane < end) ? csr_src[base + lane] : 0;   // coalesced
        int j = 0;
        for (; j + 16 <= cnt; j += 16) {
            shortx4 r0 = *reinterpret_cast<const shortx4*>(hp + (size_t)__shfl(myidx, j + 0) * OUT_DIM);
            shortx4 r1 = *reinterpret_cast<const shortx4*>(hp + (size_t)__shfl(myidx, j + 1) * OUT_DIM);
            shortx4 r2 = *reinterpret_cast<const shortx4*>(hp + (size_t)__shfl(myidx, j + 2) * OUT_DIM);
            shortx4 r3 = *reinterpret_cast<const shortx4*>(hp + (size_t)__shfl(myidx, j + 3) * OUT_DIM);
            shortx4 r4 = *reinterpret_cast<const shortx4*>(hp + (size_t)__shfl(myidx, j + 4) * OUT_DIM);
            shortx4 r5 = *reinterpret_cast<const shortx4*>(hp + (size_t)__shfl(myidx, j + 5) * OUT_DIM);
            shortx4 r6 = *reinterpret_cast<const shortx4*>(hp + (size_t)__shfl(myidx, j + 6) * OUT_DIM);
            shortx4 r7 = *reinterpret_cast<const shortx4*>(hp + (size_t)__shfl(myidx, j + 7) * OUT_DIM);
            shortx4 r8 = *reinterpret_cast<const shortx4*>(hp + (size_t)__shfl(myidx, j + 8) * OUT_DIM);
            shortx4 r9 = *reinterpret_cast<const shortx4*>(hp + (size_t)__shfl(myidx, j + 9) * OUT_DIM);
            shortx4 ra = *reinterpret_cast<const shortx4*>(hp + (size_t)__shfl(myidx, j + 10) * OUT_DIM);
            shortx4 rb = *reinterpret_cast<const shortx4*>(hp + (size_t)__shfl(myidx, j + 11) * OUT_DIM);
            shortx4 rc = *reinterpret_cast<const shortx4*>(hp + (size_t)__shfl(myidx, j + 12) * OUT_DIM);
            shortx4 rd = *reinterpret_cast<const shortx4*>(hp + (size_t)__shfl(myidx, j + 13) * OUT_DIM);
            shortx4 re = *reinterpret_cast<const shortx4*>(hp + (size_t)__shfl(myidx, j + 14) * OUT_DIM);
            shortx4 rf = *reinterpret_cast<const shortx4*>(hp + (size_t)__shfl(myidx, j + 15) * OUT_DIM);
            A2_SUM8(r0, r1, r2, r3, r4, r5, r6, r7)
            A2_SUM8(r8, r9, ra, rb, rc, rd, re, rf)
        }
        for (; j + 8 <= cnt; j += 8) {
            shortx4 r0 = *reinterpret_cast<const shortx4*>(hp + (size_t)__shfl(myidx, j + 0) * OUT_DIM);
            shortx4 r1 = *reinterpret_cast<const shortx4*>(hp + (size_t)__shfl(myidx, j + 1) * OUT_DIM);
            shortx4 r2 = *reinterpret_cast<const shortx4*>(hp + (size_t)__shfl(myidx, j + 2) * OUT_DIM);
            shortx4 r3 = *reinterpret_cast<const shortx4*>(hp + (size_t)__shfl(myidx, j + 3) * OUT_DIM);
            shortx4 r4 = *reinterpret_cast<const shortx4*>(hp + (size_t)__shfl(myidx, j + 4) * OUT_DIM);
            shortx4 r5 = *reinterpret_cast<const shortx4*>(hp + (size_t)__shfl(myidx, j + 5) * OUT_DIM);
            shortx4 r6 = *reinterpret_cast<const shortx4*>(hp + (size_t)__shfl(myidx, j + 6) * OUT_DIM);
            shortx4 r7 = *reinterpret_cast<const shortx4*>(hp + (size_t)__shfl(myidx, j + 7) * OUT_DIM);
            A2_SUM8(r0, r1, r2, r3, r4, r5, r6, r7)
        }
        for (; j < cnt; j++) {
            shortx4 r = *reinterpret_cast<const shortx4*>(hp + (size_t)__shfl(myidx, j) * OUT_DIM);
#pragma unroll
            for (int q = 0; q < 4; q++) acc[q] += bf2f((unsigned short)r[q]);
        }
    }
#undef A2_SUM8

    floatx4 o = { acc[0] * dv + b[0], acc[1] * dv + b[1],
                  acc[2] * dv + b[2], acc[3] * dv + b[3] };
    __builtin_nontemporal_store(o, reinterpret_cast<floatx4*>(out + (size_t)node * OUT_DIM + c));
}

// ---------------------------------------------------------------------------
extern "C" void kernel_launch(void* const* d_in, const int* in_sizes, int n_in,
                              void* d_out, int out_size, void* d_ws, size_t ws_size,
                              hipStream_t stream) {
    const float* x    = (const float*)d_in[0];
    const int*   edge = (const int*)d_in[1];
    const float* W1   = (const float*)d_in[2];
    const float* b1   = (const float*)d_in[3];
    const float* W2   = (const float*)d_in[4];
    const float* b2   = (const float*)d_in[5];
    float* out = (float*)d_out;

    const int* src = edge;
    const int* dst = edge + N_EDGES;

    char*  ws  = (char*)d_ws;
    size_t off = 0;
    auto alloc = [&](size_t bytes) -> void* {
        void* p = ws + off;
        off += (bytes + 255) & ~(size_t)255;
        return p;
    };
    int*   deg      = (int*)alloc((size_t)N_NODES * 4);
    float* dinv     = (float*)alloc((size_t)N_NODES * 4);
    int*   offsets  = (int*)alloc((size_t)(N_NODES + 1) * 4);
    int*   cursor   = (int*)alloc((size_t)N_NODES * 4);
    int*   csr_src  = (int*)alloc((size_t)N_EDGES * 4);
    int*   partials = (int*)alloc((size_t)N_SCAN_BLOCKS * 4);
    int*   bases    = (int*)alloc((size_t)N_SCAN_BLOCKS * 4);
    unsigned short* xhi   = (unsigned short*)alloc((size_t)M_PAD * IN_DIM * 2);
    unsigned short* xlo   = (unsigned short*)alloc((size_t)M_PAD * IN_DIM * 2);
    unsigned short* w1thi = (unsigned short*)alloc((size_t)HID_DIM * IN_DIM * 2);
    unsigned short* w1tlo = (unsigned short*)alloc((size_t)HID_DIM * IN_DIM * 2);
    unsigned short* w2thi = (unsigned short*)alloc((size_t)OUT_DIM * HID_DIM * 2);
    unsigned short* w2tlo = (unsigned short*)alloc((size_t)OUT_DIM * HID_DIM * 2);
    unsigned short* hs = (unsigned short*)alloc((size_t)N_NODES * HID_DIM * 2);  // bf16 pre-agg, reused L2

    unsigned short* y1hi = xhi;   // alias dead x regions
    unsigned short* y1lo = xlo;

    // ---- graph prep ----
    hipMemsetAsync(deg, 0, (size_t)N_NODES * 4, stream);
    count_deg_kernel<<<(N_EDGES + 255) / 256, 256, 0, stream>>>(dst, deg, N_EDGES);
    block_sum_kernel<<<N_SCAN_BLOCKS, SCAN_B, 0, stream>>>(deg, partials, N_NODES);
    scan_partials_kernel<<<1, SCAN_B, 0, stream>>>(partials, bases, N_SCAN_BLOCKS);
    finalize_scan_kernel<<<N_SCAN_BLOCKS, SCAN_B, 0, stream>>>(deg, bases, offsets, cursor,
                                                               dinv, N_NODES);
    fill_csr_kernel<<<(N_EDGES + 255) / 256, 256, 0, stream>>>(src, dst, cursor, csr_src, N_EDGES);

    // ---- precision split ----
    long long n4x = (long long)N_NODES * IN_DIM / 4;
    convert_split_kernel<<<(int)((n4x + 255) / 256), 256, 0, stream>>>(x, xhi, xlo, n4x);
    transpose_split_kernel<<<dim3(HID_DIM / 32, IN_DIM / 32), dim3(32, 32), 0, stream>>>(
        W1, w1thi, w1tlo, IN_DIM, HID_DIM);
    transpose_split_kernel<<<dim3(OUT_DIM / 32, HID_DIM / 32), dim3(32, 32), 0, stream>>>(
        W2, w2thi, w2tlo, HID_DIM, OUT_DIM);

    // ---- layer 1: 256x128 counted-vmcnt pipeline ----
    gemm1_256x128_kernel<<<dim3(HID_DIM / 128, M_PAD / 256), 512, 0, stream>>>(
        xhi, xlo, w1thi, w1tlo, dinv, hs, N_NODES, HID_DIM, IN_DIM);
    aggregate1_kernel<<<N_NODES / 4, 256, 0, stream>>>(
        hs, offsets, csr_src, dinv, b1, y1hi, y1lo);

    // ---- layer 2: r2 128-sq kernel (well-balanced grid) ----
    gemm_bf16x3_kernel<<<dim3(OUT_DIM / 128, M_PAD / 128), 256, 0, stream>>>(
        y1hi, y1lo, w2thi, w2tlo, dinv, hs, N_NODES, OUT_DIM, HID_DIM);
    aggregate2_kernel<<<N_NODES / 4, 256, 0, stream>>>(
        hs, offsets, csr_src, dinv, b2, out);
}

// Round 10
// 750.074 us; speedup vs baseline: 1.0786x; 1.0522x over previous
//
#include <hip/hip_runtime.h>

#define N_NODES 50000
#define N_EDGES 800000
#define IN_DIM  768
#define HID_DIM 512
#define OUT_DIM 256
#define M_PAD   50048   // 391 * 128

typedef __attribute__((ext_vector_type(8))) short shortx8;        // 8 bf16 = 16 B
typedef __attribute__((ext_vector_type(4))) short shortx4;        // 4 bf16 = 8 B
typedef __attribute__((ext_vector_type(4))) float floatx4;        // MFMA C/D + NT stores

#define AS1 __attribute__((address_space(1)))
#define AS3 __attribute__((address_space(3)))

__device__ __forceinline__ unsigned short f2bf_rne(float f) {
    unsigned int u = __float_as_uint(f);
    unsigned int r = u + 0x7FFFu + ((u >> 16) & 1u);
    return (unsigned short)(r >> 16);
}
__device__ __forceinline__ float bf2f(unsigned short h) {
    return __uint_as_float(((unsigned int)h) << 16);
}

// ---------------------------------------------------------------------------
// Graph prep
// ---------------------------------------------------------------------------
__global__ void count_deg_kernel(const int* __restrict__ dst, int* __restrict__ deg,
                                 int n_edges) {
    int e = blockIdx.x * blockDim.x + threadIdx.x;
    if (e < n_edges) atomicAdd(&deg[dst[e]], 1);
}

#define SCAN_B 256
#define N_SCAN_BLOCKS ((N_NODES + SCAN_B - 1) / SCAN_B)   // 196

__global__ void block_sum_kernel(const int* __restrict__ deg, int* __restrict__ partials,
                                 int n) {
    __shared__ int sm[SCAN_B];
    int i = blockIdx.x * SCAN_B + threadIdx.x;
    sm[threadIdx.x] = (i < n) ? deg[i] : 0;
    __syncthreads();
    for (int off = SCAN_B / 2; off > 0; off >>= 1) {
        if (threadIdx.x < off) sm[threadIdx.x] += sm[threadIdx.x + off];
        __syncthreads();
    }
    if (threadIdx.x == 0) partials[blockIdx.x] = sm[0];
}

__global__ void scan_partials_kernel(const int* __restrict__ partials,
                                     int* __restrict__ bases, int nb) {
    __shared__ int sm[SCAN_B];
    int v = (threadIdx.x < nb) ? partials[threadIdx.x] : 0;
    sm[threadIdx.x] = v;
    __syncthreads();
    for (int off = 1; off < SCAN_B; off <<= 1) {
        int t = (threadIdx.x >= off) ? sm[threadIdx.x - off] : 0;
        __syncthreads();
        sm[threadIdx.x] += t;
        __syncthreads();
    }
    if (threadIdx.x < nb) bases[threadIdx.x] = sm[threadIdx.x] - v;   // exclusive
}

__global__ void finalize_scan_kernel(const int* __restrict__ deg, const int* __restrict__ bases,
                                     int* __restrict__ offsets, int* __restrict__ cursor,
                                     float* __restrict__ dinv, int n) {
    __shared__ int sm[SCAN_B];
    int i = blockIdx.x * SCAN_B + threadIdx.x;
    int v = (i < n) ? deg[i] : 0;
    sm[threadIdx.x] = v;
    __syncthreads();
    for (int off = 1; off < SCAN_B; off <<= 1) {
        int t = (threadIdx.x >= off) ? sm[threadIdx.x - off] : 0;
        __syncthreads();
        sm[threadIdx.x] += t;
        __syncthreads();
    }
    if (i < n) {
        int incl = bases[blockIdx.x] + sm[threadIdx.x];
        int o = incl - v;
        offsets[i] = o;
        cursor[i]  = o;
        dinv[i]    = rsqrtf((float)(v + 1));
        if (i == n - 1) offsets[n] = incl;
    }
}

__global__ void fill_csr_kernel(const int* __restrict__ src, const int* __restrict__ dst,
                                int* __restrict__ cursor, int* __restrict__ csr_src,
                                int n_edges) {
    int e = blockIdx.x * blockDim.x + threadIdx.x;
    if (e < n_edges) {
        int p = atomicAdd(&cursor[dst[e]], 1);
        csr_src[p] = src[e];
    }
}

// ---------------------------------------------------------------------------
// fp32 -> bf16 hi/lo split
// ---------------------------------------------------------------------------
__global__ void convert_split_kernel(const float* __restrict__ x,
                                     unsigned short* __restrict__ xhi,
                                     unsigned short* __restrict__ xlo,
                                     long long n4) {
    long long i = (long long)blockIdx.x * blockDim.x + threadIdx.x;
    if (i >= n4) return;
    float4 v = *reinterpret_cast<const float4*>(x + i * 4);
    ushort4 h, l;
    h.x = f2bf_rne(v.x); l.x = f2bf_rne(v.x - bf2f(h.x));
    h.y = f2bf_rne(v.y); l.y = f2bf_rne(v.y - bf2f(h.y));
    h.z = f2bf_rne(v.z); l.z = f2bf_rne(v.z - bf2f(h.z));
    h.w = f2bf_rne(v.w); l.w = f2bf_rne(v.w - bf2f(h.w));
    *reinterpret_cast<ushort4*>(xhi + i * 4) = h;
    *reinterpret_cast<ushort4*>(xlo + i * 4) = l;
}

// ---------------------------------------------------------------------------
// W [K][N] fp32 -> Wt [N][K] bf16 hi/lo
// ---------------------------------------------------------------------------
__global__ void transpose_split_kernel(const float* __restrict__ W,
                                       unsigned short* __restrict__ Whi,
                                       unsigned short* __restrict__ Wlo,
                                       int K, int N) {
    __shared__ float tile[32][33];
    int n0 = blockIdx.x * 32, k0 = blockIdx.y * 32;
    int tx = threadIdx.x, ty = threadIdx.y;
    tile[ty][tx] = W[(size_t)(k0 + ty) * N + n0 + tx];
    __syncthreads();
    float v = tile[tx][ty];
    unsigned short h = f2bf_rne(v);
    size_t o = (size_t)(n0 + ty) * K + k0 + tx;
    Whi[o] = h;
    Wlo[o] = f2bf_rne(v - bf2f(h));
}

// ---------------------------------------------------------------------------
// bf16x3 split MFMA GEMM (VERIFIED BEST: 173.7 us layer-1, 683 TF).
//   C[r][c] = bf16( (sum_k A[r][k]*B[c][k]) * dinv[r] )
//  - T1 XCD-aware bijective block swizzle (FETCH 340->94 MB).
//  - T2 both-sides XOR swizzle (SQ_LDS_BANK_CONFLICT -> 0).
//  - SINGLE-buffer 32 KiB LDS, 2-barrier K-step. Structural-variant matrix
//    (r1..r9): 64KiB dbuf 202, vmcnt graft 204, 8-wave 256x128 212,
//    1-wave barrier-free 226, direct-B 255 -- this structure is the optimum;
//    occupancy (3-4 blk/CU at 32 KiB) is what hides the stage latency.
//  - Register diet: B-frags live across K-step, A-frags per-i. VGPR=60.
// ---------------------------------------------------------------------------
#define GBK 32

__global__ __launch_bounds__(256, 4)
void gemm_bf16x3_kernel(const unsigned short* __restrict__ Ahi,
                        const unsigned short* __restrict__ Alo,
                        const unsigned short* __restrict__ Bhi,
                        const unsigned short* __restrict__ Blo,
                        const float* __restrict__ dinv,
                        unsigned short* __restrict__ C,
                        int M, int N, int K) {
    // [hi/lo][row][k] : 2*128*32*2B = 16 KiB each, 32 KiB total
    __shared__ __align__(16) unsigned short As[2][128][GBK];
    __shared__ __align__(16) unsigned short Bs[2][128][GBK];

    const int tid  = threadIdx.x;
    const int lane = tid & 63;
    const int wave = tid >> 6;

    // --- XCD-aware bijective swizzle (m204 formula) ---
    const int gx   = gridDim.x;
    const int nwg  = gx * gridDim.y;
    const int blin = blockIdx.y * gx + blockIdx.x;      // hw linear id, x fastest
    const int qq   = nwg >> 3, rr = nwg & 7;
    const int xcd  = blin & 7, idx = blin >> 3;
    const int tt   = (xcd < rr ? xcd * (qq + 1) : rr * (qq + 1) + (xcd - rr) * qq) + idx;
    const int rowBase = (tt / gx) * 128;
    const int colBase = (tt % gx) * 128;

    const unsigned short* gsrc =
        (wave == 0) ? Ahi : (wave == 1) ? Alo : (wave == 2) ? Bhi : Blo;
    unsigned short* lbase =
        (wave == 0) ? &As[0][0][0] : (wave == 1) ? &As[1][0][0]
      : (wave == 2) ? &Bs[0][0][0] : &Bs[1][0][0];
    const int rbase = (wave < 2) ? rowBase : colBase;
    // pre-swizzled global col-group so LDS[r][s] holds col-group s ^ ((r>>1)&3)
    const int cg = ((lane & 3) ^ ((lane >> 3) & 3)) * 8;
    const size_t laneRowOff = (size_t)(rbase + (lane >> 2)) * K + cg;

    const int m0  = (wave & 1) * 64;
    const int n0  = (wave >> 1) * 64;
    const int r16 = lane & 15;
    // matching read-side XOR: logical col-group (lane>>4), physical slot XORed
    const int kswz = ((lane >> 4) ^ ((r16 >> 1) & 3)) * 8;

    floatx4 acc[4][4] = {};

    for (int k0 = 0; k0 < K; k0 += GBK) {
#pragma unroll
        for (int j = 0; j < 8; j++) {
            const unsigned short* g = gsrc + laneRowOff + (size_t)(j * 16) * K + k0;
            __builtin_amdgcn_global_load_lds((const AS1 void*)g,
                                             (AS3 void*)(lbase + j * 16 * GBK),
                                             16, 0, 0);
        }
        __syncthreads();

        // B fragments live across the whole K-step (32 VGPR)
        shortx8 bh[4], bv[4];
#pragma unroll
        for (int j = 0; j < 4; j++) {
            bh[j] = *reinterpret_cast<const shortx8*>(&Bs[0][n0 + j * 16 + r16][kswz]);
            bv[j] = *reinterpret_cast<const shortx8*>(&Bs[1][n0 + j * 16 + r16][kswz]);
        }
        // A fragments loaded per i (8 VGPR live) -> peak live ~40 regs
#pragma unroll
        for (int i = 0; i < 4; i++) {
            shortx8 ah = *reinterpret_cast<const shortx8*>(&As[0][m0 + i * 16 + r16][kswz]);
            shortx8 al = *reinterpret_cast<const shortx8*>(&As[1][m0 + i * 16 + r16][kswz]);
#pragma unroll
            for (int j = 0; j < 4; j++) {
                acc[i][j] = __builtin_amdgcn_mfma_f32_16x16x32_bf16(ah, bh[j], acc[i][j], 0, 0, 0);
                acc[i][j] = __builtin_amdgcn_mfma_f32_16x16x32_bf16(ah, bv[j], acc[i][j], 0, 0, 0);
                acc[i][j] = __builtin_amdgcn_mfma_f32_16x16x32_bf16(al, bh[j], acc[i][j], 0, 0, 0);
            }
        }
        __syncthreads();
    }

#pragma unroll
    for (int i = 0; i < 4; i++) {
        int rsub = rowBase + m0 + i * 16 + (lane >> 4) * 4;
#pragma unroll
        for (int j = 0; j < 4; j++) {
            int col = colBase + n0 + j * 16 + r16;
#pragma unroll
            for (int r = 0; r < 4; r++) {
                int row = rsub + r;
                if (row < M) C[(size_t)row * N + col] = f2bf_rne(acc[i][j][r] * dinv[row]);
            }
        }
    }
}

// ---------------------------------------------------------------------------
// Aggregation, layer 1 -- wave-per-node, barrier-free.
// 256-thr block = 4 waves = 4 nodes. Neighbor indices: coalesced one-per-lane
// load + __shfl broadcast. No LDS, no __syncthreads. 16 gather rows in flight
// (two sequential 8-trees -> bit-identical numerics).
// out = relu((hs[self] + sum hs[nbr]) * dinv + b), written bf16 hi/lo (NT).
// ---------------------------------------------------------------------------
__global__ __launch_bounds__(256)
void aggregate1_kernel(const unsigned short* __restrict__ hs, const int* __restrict__ offsets,
                       const int* __restrict__ csr_src, const float* __restrict__ dinv,
                       const float* __restrict__ bias,
                       unsigned short* __restrict__ yhi,
                       unsigned short* __restrict__ ylo) {
    const int wave = threadIdx.x >> 6;
    const int lane = threadIdx.x & 63;
    const int node = blockIdx.x * 4 + wave;
    const int c = lane * 8;
    const unsigned short* hp = hs + c;

    const int beg = offsets[node], end = offsets[node + 1];
    const float dv = dinv[node];
    floatx4 b0 = *reinterpret_cast<const floatx4*>(bias + c);
    floatx4 b1 = *reinterpret_cast<const floatx4*>(bias + c + 4);

    float acc[8];
    {
        shortx8 r = *reinterpret_cast<const shortx8*>(hp + (size_t)node * HID_DIM);
#pragma unroll
        for (int q = 0; q < 8; q++) acc[q] = bf2f((unsigned short)r[q]);
    }

#define A1_SUM8(r0,r1,r2,r3,r4,r5,r6,r7)                                        \
    _Pragma("unroll")                                                            \
    for (int q = 0; q < 8; q++)                                                  \
        acc[q] += ((bf2f((unsigned short)r0[q]) + bf2f((unsigned short)r1[q]))   \
                 + (bf2f((unsigned short)r2[q]) + bf2f((unsigned short)r3[q])))  \
                + ((bf2f((unsigned short)r4[q]) + bf2f((unsigned short)r5[q]))   \
                 + (bf2f((unsigned short)r6[q]) + bf2f((unsigned short)r7[q])));

    for (int base = beg; base < end; base += 64) {
        int cnt = min(64, end - base);
        int myidx = (base + lane < end) ? csr_src[base + lane] : 0;   // coalesced
        int j = 0;
        for (; j + 16 <= cnt; j += 16) {
            shortx8 r0 = *reinterpret_cast<const shortx8*>(hp + (size_t)__shfl(myidx, j + 0) * HID_DIM);
            shortx8 r1 = *reinterpret_cast<const shortx8*>(hp + (size_t)__shfl(myidx, j + 1) * HID_DIM);
            shortx8 r2 = *reinterpret_cast<const shortx8*>(hp + (size_t)__shfl(myidx, j + 2) * HID_DIM);
            shortx8 r3 = *reinterpret_cast<const shortx8*>(hp + (size_t)__shfl(myidx, j + 3) * HID_DIM);
            shortx8 r4 = *reinterpret_cast<const shortx8*>(hp + (size_t)__shfl(myidx, j + 4) * HID_DIM);
            shortx8 r5 = *reinterpret_cast<const shortx8*>(hp + (size_t)__shfl(myidx, j + 5) * HID_DIM);
            shortx8 r6 = *reinterpret_cast<const shortx8*>(hp + (size_t)__shfl(myidx, j + 6) * HID_DIM);
            shortx8 r7 = *reinterpret_cast<const shortx8*>(hp + (size_t)__shfl(myidx, j + 7) * HID_DIM);
            shortx8 r8 = *reinterpret_cast<const shortx8*>(hp + (size_t)__shfl(myidx, j + 8) * HID_DIM);
            shortx8 r9 = *reinterpret_cast<const shortx8*>(hp + (size_t)__shfl(myidx, j + 9) * HID_DIM);
            shortx8 ra = *reinterpret_cast<const shortx8*>(hp + (size_t)__shfl(myidx, j + 10) * HID_DIM);
            shortx8 rb = *reinterpret_cast<const shortx8*>(hp + (size_t)__shfl(myidx, j + 11) * HID_DIM);
            shortx8 rc = *reinterpret_cast<const shortx8*>(hp + (size_t)__shfl(myidx, j + 12) * HID_DIM);
            shortx8 rd = *reinterpret_cast<const shortx8*>(hp + (size_t)__shfl(myidx, j + 13) * HID_DIM);
            shortx8 re = *reinterpret_cast<const shortx8*>(hp + (size_t)__shfl(myidx, j + 14) * HID_DIM);
            shortx8 rf = *reinterpret_cast<const shortx8*>(hp + (size_t)__shfl(myidx, j + 15) * HID_DIM);
            A1_SUM8(r0, r1, r2, r3, r4, r5, r6, r7)
            A1_SUM8(r8, r9, ra, rb, rc, rd, re, rf)
        }
        for (; j + 8 <= cnt; j += 8) {
            shortx8 r0 = *reinterpret_cast<const shortx8*>(hp + (size_t)__shfl(myidx, j + 0) * HID_DIM);
            shortx8 r1 = *reinterpret_cast<const shortx8*>(hp + (size_t)__shfl(myidx, j + 1) * HID_DIM);
            shortx8 r2 = *reinterpret_cast<const shortx8*>(hp + (size_t)__shfl(myidx, j + 2) * HID_DIM);
            shortx8 r3 = *reinterpret_cast<const shortx8*>(hp + (size_t)__shfl(myidx, j + 3) * HID_DIM);
            shortx8 r4 = *reinterpret_cast<const shortx8*>(hp + (size_t)__shfl(myidx, j + 4) * HID_DIM);
            shortx8 r5 = *reinterpret_cast<const shortx8*>(hp + (size_t)__shfl(myidx, j + 5) * HID_DIM);
            shortx8 r6 = *reinterpret_cast<const shortx8*>(hp + (size_t)__shfl(myidx, j + 6) * HID_DIM);
            shortx8 r7 = *reinterpret_cast<const shortx8*>(hp + (size_t)__shfl(myidx, j + 7) * HID_DIM);
            A1_SUM8(r0, r1, r2, r3, r4, r5, r6, r7)
        }
        for (; j < cnt; j++) {
            shortx8 r = *reinterpret_cast<const shortx8*>(hp + (size_t)__shfl(myidx, j) * HID_DIM);
#pragma unroll
            for (int q = 0; q < 8; q++) acc[q] += bf2f((unsigned short)r[q]);
        }
    }
#undef A1_SUM8

    shortx8 h8, l8;
#pragma unroll
    for (int q = 0; q < 8; q++) {
        float bq = (q < 4) ? b0[q] : b1[q - 4];
        float o = fmaxf(acc[q] * dv + bq, 0.f);
        unsigned short h = f2bf_rne(o);
        h8[q] = (short)h;
        l8[q] = (short)f2bf_rne(o - bf2f(h));
    }
    __builtin_nontemporal_store(h8, reinterpret_cast<shortx8*>(yhi + (size_t)node * HID_DIM + c));
    __builtin_nontemporal_store(l8, reinterpret_cast<shortx8*>(ylo + (size_t)node * HID_DIM + c));
}

// ---------------------------------------------------------------------------
// Aggregation, layer 2 -- wave-per-node (F=256, 8 B/lane/row). fp32 out, NT.
// ---------------------------------------------------------------------------
__global__ __launch_bounds__(256)
void aggregate2_kernel(const unsigned short* __restrict__ hs, const int* __restrict__ offsets,
                       const int* __restrict__ csr_src, const float* __restrict__ dinv,
                       const float* __restrict__ bias, float* __restrict__ out) {
    const int wave = threadIdx.x >> 6;
    const int lane = threadIdx.x & 63;
    const int node = blockIdx.x * 4 + wave;
    const int c = lane * 4;
    const unsigned short* hp = hs + c;

    const int beg = offsets[node], end = offsets[node + 1];
    const float dv = dinv[node];
    floatx4 b = *reinterpret_cast<const floatx4*>(bias + c);

    float acc[4];
    {
        shortx4 r = *reinterpret_cast<const shortx4*>(hp + (size_t)node * OUT_DIM);
#pragma unroll
        for (int q = 0; q < 4; q++) acc[q] = bf2f((unsigned short)r[q]);
    }

#define A2_SUM8(r0,r1,r2,r3,r4,r5,r6,r7)                                        \
    _Pragma("unroll")                                                            \
    for (int q = 0; q < 4; q++)                                                  \
        acc[q] += ((bf2f((unsigned short)r0[q]) + bf2f((unsigned short)r1[q]))   \
                 + (bf2f((unsigned short)r2[q]) + bf2f((unsigned short)r3[q])))  \
                + ((bf2f((unsigned short)r4[q]) + bf2f((unsigned short)r5[q]))   \
                 + (bf2f((unsigned short)r6[q]) + bf2f((unsigned short)r7[q])));

    for (int base = beg; base < end; base += 64) {
        int cnt = min(64, end - base);
        int myidx = (base + lane < end) ? csr_src[base + lane] : 0;   // coalesced
        int j = 0;
        for (; j + 16 <= cnt; j += 16) {
            shortx4 r0 = *reinterpret_cast<const shortx4*>(hp + (size_t)__shfl(myidx, j + 0) * OUT_DIM);
            shortx4 r1 = *reinterpret_cast<const shortx4*>(hp + (size_t)__shfl(myidx, j + 1) * OUT_DIM);
            shortx4 r2 = *reinterpret_cast<const shortx4*>(hp + (size_t)__shfl(myidx, j + 2) * OUT_DIM);
            shortx4 r3 = *reinterpret_cast<const shortx4*>(hp + (size_t)__shfl(myidx, j + 3) * OUT_DIM);
            shortx4 r4 = *reinterpret_cast<const shortx4*>(hp + (size_t)__shfl(myidx, j + 4) * OUT_DIM);
            shortx4 r5 = *reinterpret_cast<const shortx4*>(hp + (size_t)__shfl(myidx, j + 5) * OUT_DIM);
            shortx4 r6 = *reinterpret_cast<const shortx4*>(hp + (size_t)__shfl(myidx, j + 6) * OUT_DIM);
            shortx4 r7 = *reinterpret_cast<const shortx4*>(hp + (size_t)__shfl(myidx, j + 7) * OUT_DIM);
            shortx4 r8 = *reinterpret_cast<const shortx4*>(hp + (size_t)__shfl(myidx, j + 8) * OUT_DIM);
            shortx4 r9 = *reinterpret_cast<const shortx4*>(hp + (size_t)__shfl(myidx, j + 9) * OUT_DIM);
            shortx4 ra = *reinterpret_cast<const shortx4*>(hp + (size_t)__shfl(myidx, j + 10) * OUT_DIM);
            shortx4 rb = *reinterpret_cast<const shortx4*>(hp + (size_t)__shfl(myidx, j + 11) * OUT_DIM);
            shortx4 rc = *reinterpret_cast<const shortx4*>(hp + (size_t)__shfl(myidx, j + 12) * OUT_DIM);
            shortx4 rd = *reinterpret_cast<const shortx4*>(hp + (size_t)__shfl(myidx, j + 13) * OUT_DIM);
            shortx4 re = *reinterpret_cast<const shortx4*>(hp + (size_t)__shfl(myidx, j + 14) * OUT_DIM);
            shortx4 rf = *reinterpret_cast<const shortx4*>(hp + (size_t)__shfl(myidx, j + 15) * OUT_DIM);
            A2_SUM8(r0, r1, r2, r3, r4, r5, r6, r7)
            A2_SUM8(r8, r9, ra, rb, rc, rd, re, rf)
        }
        for (; j + 8 <= cnt; j += 8) {
            shortx4 r0 = *reinterpret_cast<const shortx4*>(hp + (size_t)__shfl(myidx, j + 0) * OUT_DIM);
            shortx4 r1 = *reinterpret_cast<const shortx4*>(hp + (size_t)__shfl(myidx, j + 1) * OUT_DIM);
            shortx4 r2 = *reinterpret_cast<const shortx4*>(hp + (size_t)__shfl(myidx, j + 2) * OUT_DIM);
            shortx4 r3 = *reinterpret_cast<const shortx4*>(hp + (size_t)__shfl(myidx, j + 3) * OUT_DIM);
            shortx4 r4 = *reinterpret_cast<const shortx4*>(hp + (size_t)__shfl(myidx, j + 4) * OUT_DIM);
            shortx4 r5 = *reinterpret_cast<const shortx4*>(hp + (size_t)__shfl(myidx, j + 5) * OUT_DIM);
            shortx4 r6 = *reinterpret_cast<const shortx4*>(hp + (size_t)__shfl(myidx, j + 6) * OUT_DIM);
            shortx4 r7 = *reinterpret_cast<const shortx4*>(hp + (size_t)__shfl(myidx, j + 7) * OUT_DIM);
            A2_SUM8(r0, r1, r2, r3, r4, r5, r6, r7)
        }
        for (; j < cnt; j++) {
            shortx4 r = *reinterpret_cast<const shortx4*>(hp + (size_t)__shfl(myidx, j) * OUT_DIM);
#pragma unroll
            for (int q = 0; q < 4; q++) acc[q] += bf2f((unsigned short)r[q]);
        }
    }
#undef A2_SUM8

    floatx4 o = { acc[0] * dv + b[0], acc[1] * dv + b[1],
                  acc[2] * dv + b[2], acc[3] * dv + b[3] };
    __builtin_nontemporal_store(o, reinterpret_cast<floatx4*>(out + (size_t)node * OUT_DIM + c));
}

// ---------------------------------------------------------------------------
extern "C" void kernel_launch(void* const* d_in, const int* in_sizes, int n_in,
                              void* d_out, int out_size, void* d_ws, size_t ws_size,
                              hipStream_t stream) {
    const float* x    = (const float*)d_in[0];
    const int*   edge = (const int*)d_in[1];
    const float* W1   = (const float*)d_in[2];
    const float* b1   = (const float*)d_in[3];
    const float* W2   = (const float*)d_in[4];
    const float* b2   = (const float*)d_in[5];
    float* out = (float*)d_out;

    const int* src = edge;
    const int* dst = edge + N_EDGES;

    char*  ws  = (char*)d_ws;
    size_t off = 0;
    auto alloc = [&](size_t bytes) -> void* {
        void* p = ws + off;
        off += (bytes + 255) & ~(size_t)255;
        return p;
    };
    int*   deg      = (int*)alloc((size_t)N_NODES * 4);
    float* dinv     = (float*)alloc((size_t)N_NODES * 4);
    int*   offsets  = (int*)alloc((size_t)(N_NODES + 1) * 4);
    int*   cursor   = (int*)alloc((size_t)N_NODES * 4);
    int*   csr_src  = (int*)alloc((size_t)N_EDGES * 4);
    int*   partials = (int*)alloc((size_t)N_SCAN_BLOCKS * 4);
    int*   bases    = (int*)alloc((size_t)N_SCAN_BLOCKS * 4);
    unsigned short* xhi   = (unsigned short*)alloc((size_t)M_PAD * IN_DIM * 2);
    unsigned short* xlo   = (unsigned short*)alloc((size_t)M_PAD * IN_DIM * 2);
    unsigned short* w1thi = (unsigned short*)alloc((size_t)HID_DIM * IN_DIM * 2);
    unsigned short* w1tlo = (unsigned short*)alloc((size_t)HID_DIM * IN_DIM * 2);
    unsigned short* w2thi = (unsigned short*)alloc((size_t)OUT_DIM * HID_DIM * 2);
    unsigned short* w2tlo = (unsigned short*)alloc((size_t)OUT_DIM * HID_DIM * 2);
    unsigned short* hs = (unsigned short*)alloc((size_t)N_NODES * HID_DIM * 2);  // bf16 pre-agg, reused L2

    unsigned short* y1hi = xhi;   // alias dead x regions
    unsigned short* y1lo = xlo;

    // ---- graph prep ----
    hipMemsetAsync(deg, 0, (size_t)N_NODES * 4, stream);
    count_deg_kernel<<<(N_EDGES + 255) / 256, 256, 0, stream>>>(dst, deg, N_EDGES);
    block_sum_kernel<<<N_SCAN_BLOCKS, SCAN_B, 0, stream>>>(deg, partials, N_NODES);
    scan_partials_kernel<<<1, SCAN_B, 0, stream>>>(partials, bases, N_SCAN_BLOCKS);
    finalize_scan_kernel<<<N_SCAN_BLOCKS, SCAN_B, 0, stream>>>(deg, bases, offsets, cursor,
                                                               dinv, N_NODES);
    fill_csr_kernel<<<(N_EDGES + 255) / 256, 256, 0, stream>>>(src, dst, cursor, csr_src, N_EDGES);

    // ---- precision split ----
    long long n4x = (long long)N_NODES * IN_DIM / 4;
    convert_split_kernel<<<(int)((n4x + 255) / 256), 256, 0, stream>>>(x, xhi, xlo, n4x);
    transpose_split_kernel<<<dim3(HID_DIM / 32, IN_DIM / 32), dim3(32, 32), 0, stream>>>(
        W1, w1thi, w1tlo, IN_DIM, HID_DIM);
    transpose_split_kernel<<<dim3(OUT_DIM / 32, HID_DIM / 32), dim3(32, 32), 0, stream>>>(
        W2, w2thi, w2tlo, HID_DIM, OUT_DIM);

    // ---- layer 1 ----
    gemm_bf16x3_kernel<<<dim3(HID_DIM / 128, M_PAD / 128), 256, 0, stream>>>(
        xhi, xlo, w1thi, w1tlo, dinv, hs, N_NODES, HID_DIM, IN_DIM);
    aggregate1_kernel<<<N_NODES / 4, 256, 0, stream>>>(
        hs, offsets, csr_src, dinv, b1, y1hi, y1lo);

    // ---- layer 2 ----
    gemm_bf16x3_kernel<<<dim3(OUT_DIM / 128, M_PAD / 128), 256, 0, stream>>>(
        y1hi, y1lo, w2thi, w2tlo, dinv, hs, N_NODES, OUT_DIM, HID_DIM);
    aggregate2_kernel<<<N_NODES / 4, 256, 0, stream>>>(
        hs, offsets, csr_src, dinv, b2, out);
}